// Round 13
// baseline (527.140 us; speedup 1.0000x reference)
//
#include <hip/hip_runtime.h>
#include <hip/hip_fp16.h>
#include <hip/hip_cooperative_groups.h>
#include <math.h>

namespace cg = cooperative_groups;

#define N_NODES 100000
#define N_GRAPHS 512
#define F 16
#define NEG_SLOPE 0.2f
#define DMAX 80        // max CSR slots/node; deg ~ Poisson(32)
#define NSLOT 64       // global-max staging slots
#define NBUCK 391      // ceil(N_NODES/256): bucket = dst >> 8
#define BCAP 8704      // bucket capacity
#define NBLK 256       // cooperative grid: 1 block/CU
#define BT 1024        // threads/block (16 waves)
#define EPB 4          // edges/thread in partition (tile = 4096)
#define GPB 128        // 8-lane groups (nodes) per block-chunk
#define NCHUNK ((N_NODES + GPB - 1) / GPB)   // 782

__device__ __forceinline__ float lrelu(float v) {
    return v > 0.0f ? v : NEG_SLOPE * v;
}
__device__ __forceinline__ unsigned fkey(float f) {
    unsigned b = __float_as_uint(f);
    return (b & 0x80000000u) ? ~b : (b | 0x80000000u);
}
__device__ __forceinline__ float funkey(unsigned k) {
    unsigned b = (k & 0x80000000u) ? (k ^ 0x80000000u) : ~k;
    return __uint_as_float(b);
}
__device__ __forceinline__ float pe_unpack(unsigned v) {
    return __half2float(__ushort_as_half((unsigned short)(v >> 17)));
}
__device__ __forceinline__ unsigned pe_pack(int s, float pe) {
    return (unsigned)s | ((unsigned)__half_as_ushort(__float2half(pe)) << 17);
}
__device__ __forceinline__ float slot_max_c(const unsigned* __restrict__ cs,
                                            const unsigned* __restrict__ cd) {
    unsigned ms = 0, md = 0;
#pragma unroll 8
    for (int i = 0; i < NSLOT; ++i) {
        ms = max(ms, cs[i]);
        md = max(md, cd[i]);
    }
    return lrelu(funkey(ms) + funkey(md));
}

// 8-lane-group GAT aggregation (lane l owns features {2l,2l+1}); pe is
// precomputed & packed in col bits [31:17]; ONE shuffle per edge.
__device__ __forceinline__ float2 gat_agg8(int n, int l,
                                           const int* __restrict__ deg,
                                           const unsigned* __restrict__ col,
                                           const float* __restrict__ ssrc,
                                           const float* __restrict__ sdst,
                                           const unsigned* __restrict__ hX,
                                           const float* __restrict__ b,
                                           float c) {
    int dg = deg[n];
    size_t st = (size_t)n * DMAX;
    float ax = 0.f, ay = 0.f, ssum = 0.f;
    int base = 0;
    for (; base + 8 <= dg; base += 8) {
        unsigned v = __builtin_nontemporal_load(&col[st + base + l]);
        ssum += pe_unpack(v);
#pragma unroll
        for (int k = 0; k < 8; ++k) {
            unsigned vk = __shfl(v, k, 8);
            int sk = (int)(vk & 0x1FFFFu);
            float pk = pe_unpack(vk);
            unsigned hw = hX[sk * 8 + l];
            ax += pk * __half2float(__ushort_as_half((unsigned short)(hw & 0xFFFFu)));
            ay += pk * __half2float(__ushort_as_half((unsigned short)(hw >> 16)));
        }
    }
    if (base < dg) {
        int j = base + l;
        unsigned v = 0;
        if (j < dg) {
            v = __builtin_nontemporal_load(&col[st + j]);
            ssum += pe_unpack(v);
        }
        int cnt = dg - base;
        for (int k = 0; k < cnt; ++k) {
            unsigned vk = __shfl(v, k, 8);
            int sk = (int)(vk & 0x1FFFFu);
            float pk = pe_unpack(vk);
            unsigned hw = hX[sk * 8 + l];
            ax += pk * __half2float(__ushort_as_half((unsigned short)(hw & 0xFFFFu)));
            ay += pk * __half2float(__ushort_as_half((unsigned short)(hw >> 16)));
        }
    }
#pragma unroll
    for (int o = 1; o < 8; o <<= 1) ssum += __shfl_xor(ssum, o, 8);
    float pes = __expf(lrelu(ssrc[n] + sdst[n]) - c);   // self loop, f32
    unsigned hw = hX[n * 8 + l];
    ax += pes * __half2float(__ushort_as_half((unsigned short)(hw & 0xFFFFu)));
    ay += pes * __half2float(__ushort_as_half((unsigned short)(hw >> 16)));
    ssum += pes;
    float inv = 1.f / (ssum + 1e-16f);
    float2 of;
    of.x = fmaxf(ax * inv + b[2 * l], 0.f);
    of.y = fmaxf(ay * inv + b[2 * l + 1], 0.f);
    return of;
}

// ---------------------------------------------------------------------------
// ONE cooperative kernel: zero -> part||prep -> fill(+pe1) -> gather1 ->
// pe2 -> gather2(+pool) -> final, with grid.sync() between phases.
// ---------------------------------------------------------------------------
__global__ __launch_bounds__(BT, 4) void k_mega(
        const int* __restrict__ esrc, const int* __restrict__ edst,
        int E0, int nT, int nPrep,
        int* __restrict__ bcur, unsigned* __restrict__ bucket,
        const float* __restrict__ x, const float* __restrict__ W1,
        const float* __restrict__ as1, const float* __restrict__ ad1,
        unsigned* __restrict__ h1x, float* __restrict__ ssrc1,
        float* __restrict__ sdst1, unsigned* __restrict__ cs1,
        unsigned* __restrict__ cd1,
        unsigned* __restrict__ col, int* __restrict__ deg,
        const float* __restrict__ b1, const float* __restrict__ W2,
        const float* __restrict__ as2, const float* __restrict__ ad2,
        unsigned* __restrict__ h2x, float* __restrict__ ssrc2,
        float* __restrict__ sdst2, unsigned* __restrict__ cs2,
        unsigned* __restrict__ cd2,
        const int* __restrict__ bat, float* __restrict__ gsum,
        float* __restrict__ gcnt,
        const float* __restrict__ b2, const float* __restrict__ Wf,
        const float* __restrict__ bf, float* __restrict__ out,
        int* __restrict__ zbase, int nzero) {
    cg::grid_group grid = cg::this_grid();
    const int tid = threadIdx.x;
    const int bid = blockIdx.x;
    __shared__ alignas(16) char smem[GPB * 17 * 4];   // 8704 B, phase-reused

    // ---- phase 0: zero control region (bcur, cs/cd slots, gsum, gcnt) ----
    for (int i = bid * BT + tid; i < nzero; i += NBLK * BT) zbase[i] = 0;
    grid.sync();

    // ---- phase 1: partition tiles + node prep (independent, interleaved) --
    {
        int* hist  = (int*)smem;
        int* gbase = hist + NBUCK;
        int* off   = gbase + NBUCK;
        for (int w = bid; w < nT + nPrep; w += NBLK) {
            if (w < nT) {
                __syncthreads();               // protect hist reuse
                int tbase = w * (BT * EPB);
                if (tid < NBUCK) hist[tid] = 0;
                __syncthreads();
                int rb[EPB]; unsigned rv[EPB];
#pragma unroll
                for (int i = 0; i < EPB; ++i) {
                    int e = tbase + i * BT + tid;
                    rb[i] = -1;
                    if (e < E0) {
                        int d = edst[e], s = esrc[e];
                        rb[i] = d >> 8;
                        rv[i] = (unsigned)s | ((unsigned)(d & 255) << 17);
                        atomicAdd(&hist[rb[i]], 1);
                    }
                }
                __syncthreads();
                if (tid < NBUCK) {
                    int h = hist[tid];
                    gbase[tid] = h ? atomicAdd(&bcur[tid], h) : 0;
                    off[tid] = 0;
                }
                __syncthreads();
#pragma unroll
                for (int i = 0; i < EPB; ++i) {
                    int b = rb[i];
                    if (b >= 0) {
                        int p = gbase[b] + atomicAdd(&off[b], 1);
                        if (p < BCAP) bucket[(size_t)b * BCAP + p] = rv[i];
                    }
                }
            } else {
                int n = (w - nT) * BT + tid;
                float ss = -INFINITY, sd = -INFINITY;
                if (n < N_NODES) {
                    float xi[5];
#pragma unroll
                    for (int i = 0; i < 5; ++i) xi[i] = x[n * 5 + i];
                    ss = 0.f; sd = 0.f;
#pragma unroll
                    for (int f = 0; f < F; ++f) {
                        float acc = 0.f;
#pragma unroll
                        for (int i = 0; i < 5; ++i) acc += xi[i] * W1[i * F + f];
                        ((__half*)h1x)[n * F + f] = __float2half(acc);
                        ss += acc * as1[f];
                        sd += acc * ad1[f];
                    }
                    ssrc1[n] = ss;
                    sdst1[n] = sd;
                }
                unsigned ks = fkey(ss), kd = fkey(sd);
#pragma unroll
                for (int o = 32; o; o >>= 1) {
                    ks = max(ks, (unsigned)__shfl_xor((int)ks, o, 64));
                    kd = max(kd, (unsigned)__shfl_xor((int)kd, o, 64));
                }
                if ((tid & 63) == 0) {
                    int slot = (w * 16 + (tid >> 6)) & (NSLOT - 1);
                    atomicMax(&cs1[slot], ks);
                    atomicMax(&cd1[slot], kd);
                }
            }
        }
    }
    grid.sync();

    // ---- phase 2: bucketed CSR fill + layer-1 pe pack ----
    {
        int* cur   = (int*)smem;
        float* sdl = (float*)(cur + 256);
        float c1 = slot_max_c(cs1, cd1);
        for (int b = bid; b < NBUCK; b += NBLK) {
            if (tid < 256) {
                cur[tid] = 0;
                int dst = (b << 8) | tid;
                sdl[tid] = (dst < N_NODES) ? sdst1[dst] : 0.f;
            }
            __syncthreads();
            int cnt = min(bcur[b], BCAP);
            const unsigned* bk = bucket + (size_t)b * BCAP;
            for (int i = tid; i < cnt; i += BT) {
                unsigned v = __builtin_nontemporal_load(&bk[i]);
                int s = (int)(v & 0x1FFFFu);
                int dl = (int)(v >> 17);
                int r = atomicAdd(&cur[dl], 1);
                if (r < DMAX) {
                    float pe = __expf(lrelu(ssrc1[s] + sdl[dl]) - c1);
                    col[((size_t)((b << 8) | dl)) * DMAX + r] = pe_pack(s, pe);
                }
            }
            __syncthreads();
            if (tid < 256) {
                int dst = (b << 8) | tid;
                if (dst < N_NODES) deg[dst] = min(cur[tid], DMAX);
            }
        }
    }
    grid.sync();

    // ---- phase 3: layer-1 gather + fused layer-2 prep ----
    {
        float (*lho)[17] = (float (*)[17])smem;
        float c1 = slot_max_c(cs1, cd1);
        int gid = tid >> 3, l = tid & 7;
        for (int c = bid; c < NCHUNK; c += NBLK) {
            int n = c * GPB + gid;
            bool valid = n < N_NODES;
            int nc = valid ? n : 0;
            float2 of = gat_agg8(nc, l, deg, col, ssrc1, sdst1, h1x, b1, c1);
            // lho[gid] only touched by this 8-lane group (same wave): no barrier
            lho[gid][2 * l] = of.x;
            lho[gid][2 * l + 1] = of.y;
            float hx = 0.f, hy = 0.f;
#pragma unroll
            for (int i = 0; i < 16; ++i) {
                float hoi = lho[gid][i];
                hx += hoi * W2[i * F + 2 * l];
                hy += hoi * W2[i * F + 2 * l + 1];
            }
            float ps = hx * as2[2 * l] + hy * as2[2 * l + 1];
            float pd = hx * ad2[2 * l] + hy * ad2[2 * l + 1];
#pragma unroll
            for (int o = 1; o < 8; o <<= 1) {
                ps += __shfl_xor(ps, o, 8);
                pd += __shfl_xor(pd, o, 8);
            }
            if (valid) {
                h2x[n * 8 + l] = (unsigned)__half_as_ushort(__float2half(hx)) |
                                 ((unsigned)__half_as_ushort(__float2half(hy)) << 16);
                if (l == 0) { ssrc2[n] = ps; sdst2[n] = pd; }
            } else {
                ps = -INFINITY; pd = -INFINITY;
            }
            unsigned ks = fkey(ps), kd = fkey(pd);
#pragma unroll
            for (int o = 8; o < 64; o <<= 1) {
                ks = max(ks, (unsigned)__shfl_xor((int)ks, o, 64));
                kd = max(kd, (unsigned)__shfl_xor((int)kd, o, 64));
            }
            if ((tid & 63) == 0) {
                int slot = (c * 16 + (tid >> 6)) & (NSLOT - 1);
                atomicMax(&cs2[slot], ks);
                atomicMax(&cd2[slot], kd);
            }
        }
    }
    grid.sync();

    // ---- phase 4: rewrite col pe bits for layer 2 ----
    {
        float c2 = slot_max_c(cs2, cd2);
        int gid = tid >> 3, l = tid & 7;
        for (int c = bid; c < NCHUNK; c += NBLK) {
            int n = c * GPB + gid;
            if (n < N_NODES) {
                int dg = deg[n];
                size_t st = (size_t)n * DMAX;
                float sd = sdst2[n];
                for (int j = l; j < dg; j += 8) {
                    unsigned v = col[st + j];
                    int s = (int)(v & 0x1FFFFu);
                    float pe = __expf(lrelu(ssrc2[s] + sd) - c2);
                    col[st + j] = pe_pack(s, pe);
                }
            }
        }
    }
    grid.sync();

    // ---- phase 5: layer-2 gather + LDS-staged mean-pool ----
    {
        float* pool = (float*)smem;       // 64 floats
        float* pcnt = pool + 4 * F;       // 4 floats
        float c2 = slot_max_c(cs2, cd2);
        int gid = tid >> 3, l = tid & 7;
        for (int c = bid; c < NCHUNK; c += NBLK) {
            if (tid < 4 * F) pool[tid] = 0.f;
            if (tid < 4) pcnt[tid] = 0.f;
            __syncthreads();
            int n = c * GPB + gid;
            bool valid = n < N_NODES;
            int nc = valid ? n : 0;
            float2 of = gat_agg8(nc, l, deg, col, ssrc2, sdst2, h2x, b2, c2);
            int g0 = bat[c * GPB];
            if (valid) {
                int g = bat[n];
                int idx = g - g0;
                if (idx < 4) {
                    atomicAdd(&pool[idx * F + 2 * l], of.x);
                    atomicAdd(&pool[idx * F + 2 * l + 1], of.y);
                    if (l == 0) atomicAdd(&pcnt[idx], 1.f);
                } else {
                    atomicAdd(&gsum[g * F + 2 * l], of.x);
                    atomicAdd(&gsum[g * F + 2 * l + 1], of.y);
                    if (l == 0) atomicAdd(&gcnt[g], 1.f);
                }
            }
            __syncthreads();
            if (tid < 4 * F) {
                float v = pool[tid];
                if (v != 0.f)
                    atomicAdd(&gsum[(g0 + (tid >> 4)) * F + (tid & 15)], v);
            }
            if (tid < 4) {
                float cv = pcnt[tid];
                if (cv != 0.f) atomicAdd(&gcnt[g0 + tid], cv);
            }
            __syncthreads();
        }
    }
    grid.sync();

    // ---- phase 6: readout ----
    if (bid == 0 && tid < N_GRAPHS) {
        int g = tid;
        float inv = 1.f / fmaxf(gcnt[g], 1.f);
        float o0 = bf[0], o1 = bf[1];
#pragma unroll
        for (int i = 0; i < F; ++i) {
            float p = gsum[g * F + i] * inv;
            o0 += p * Wf[i * 2 + 0];
            o1 += p * Wf[i * 2 + 1];
        }
        out[g * 2 + 0] = o0;
        out[g * 2 + 1] = o1;
    }
}

extern "C" void kernel_launch(void* const* d_in, const int* in_sizes, int n_in,
                              void* d_out, int out_size, void* d_ws, size_t ws_size,
                              hipStream_t stream) {
    const float* x   = (const float*)d_in[0];
    const int*   ei  = (const int*)d_in[1];
    const int*   bat = (const int*)d_in[2];
    const float* W1  = (const float*)d_in[3];
    const float* as1 = (const float*)d_in[4];
    const float* ad1 = (const float*)d_in[5];
    const float* b1  = (const float*)d_in[6];
    const float* W2  = (const float*)d_in[7];
    const float* as2 = (const float*)d_in[8];
    const float* ad2 = (const float*)d_in[9];
    const float* b2  = (const float*)d_in[10];
    const float* Wf  = (const float*)d_in[11];
    const float* bf  = (const float*)d_in[12];
    float* out = (float*)d_out;

    int E0 = in_sizes[1] / 2;   // 3,200,000 real edges
    const int* esrc = ei;
    const int* edst = ei + E0;

    // ---- workspace layout (same as round 12) ----
    unsigned* h1x  = (unsigned*)d_ws;                    // N*F halves (3.2 MB)
    unsigned* h2x  = h1x + (size_t)N_NODES * 8;          // N*F halves (3.2 MB)
    float* ssrc1 = (float*)(h2x + (size_t)N_NODES * 8);  // N
    float* sdst1 = ssrc1 + N_NODES;                      // N
    float* ssrc2 = sdst1 + N_NODES;                      // N
    float* sdst2 = ssrc2 + N_NODES;                      // N
    unsigned* col = (unsigned*)(sdst2 + N_NODES);        // N*DMAX (32 MB)
    int*   deg   = (int*)(col + (size_t)N_NODES * DMAX); // N
    unsigned* bucket = (unsigned*)(deg + N_NODES);       // NBUCK*BCAP (13.6 MB)
    // ---- zeroed-in-kernel control region ----
    int*      zbase = (int*)(bucket + (size_t)NBUCK * BCAP);
    int*      bcur  = zbase;                             // NBUCK
    unsigned* cs1   = (unsigned*)(bcur + NBUCK);         // NSLOT
    unsigned* cd1   = cs1 + NSLOT;
    unsigned* cs2   = cd1 + NSLOT;
    unsigned* cd2   = cs2 + NSLOT;
    float*    gsum  = (float*)(cd2 + NSLOT);             // G*F
    float*    gcnt  = gsum + (size_t)N_GRAPHS * F;       // G
    int nzero = NBUCK + 4 * NSLOT + N_GRAPHS * F + N_GRAPHS;   // 9351 words

    int nT = (E0 + BT * EPB - 1) / (BT * EPB);           // 782 tiles
    int nPrep = (N_NODES + BT - 1) / BT;                 // 98 chunks

    void* args[] = {
        (void*)&esrc, (void*)&edst, (void*)&E0, (void*)&nT, (void*)&nPrep,
        (void*)&bcur, (void*)&bucket,
        (void*)&x, (void*)&W1, (void*)&as1, (void*)&ad1,
        (void*)&h1x, (void*)&ssrc1, (void*)&sdst1, (void*)&cs1, (void*)&cd1,
        (void*)&col, (void*)&deg,
        (void*)&b1, (void*)&W2, (void*)&as2, (void*)&ad2,
        (void*)&h2x, (void*)&ssrc2, (void*)&sdst2, (void*)&cs2, (void*)&cd2,
        (void*)&bat, (void*)&gsum, (void*)&gcnt,
        (void*)&b2, (void*)&Wf, (void*)&bf, (void*)&out,
        (void*)&zbase, (void*)&nzero
    };
    hipLaunchCooperativeKernel((void*)k_mega, dim3(NBLK), dim3(BT),
                               args, 0, stream);
}